// Round 4
// baseline (347.851 us; speedup 1.0000x reference)
//
#include <hip/hip_runtime.h>
#include <math.h>

// HierDSFeedForward — round 4: LDS-bounce swiglu epilogue; gemm_out reverted
// mapping + t+2 counted-vmcnt double-buffer pipeline (2 blocks/CU).
// S=4096 tokens, C=1024, H=2048, 8 experts (2 groups x 4), top-2.

#define C_DIM 1024
#define H_DIM 2048
#define S_TOK 4096

typedef _Float16 f16x8 __attribute__((ext_vector_type(8)));
typedef float f32x4 __attribute__((ext_vector_type(4)));

#define AS3(p) ((__attribute__((address_space(3))) void*)(p))
#define AS1c(p) ((const __attribute__((address_space(1))) void*)(p))

// ---------------- fused fp32 -> fp16 convert (+ swiglu-pair row permutation) ----
__global__ __launch_bounds__(256) void cvt_all(
    const float* __restrict__ x, const float* __restrict__ w_in,
    const float* __restrict__ w1, const float* __restrict__ w_out,
    const float* __restrict__ w2, _Float16* __restrict__ xh,
    _Float16* __restrict__ wprime, _Float16* __restrict__ wouth,
    _Float16* __restrict__ w2h) {
  int i = blockIdx.x * 256 + threadIdx.x;  // 8-element chunk index
  const float* s; _Float16* d; size_t soff, doff;
  if (i < 524288) { s = x; d = xh; soff = doff = (size_t)i; }
  else if (i < 1572864) {
    int n = i - 524288;
    int out_row = n >> 7, kc = n & 127;
    int wmat = out_row >> 12, r = out_row & 4095;
    int g = r >> 5, ii = r & 31;
    int src_row = (ii < 16) ? (g * 16 + ii) : (2048 + g * 16 + (ii - 16));
    s = wmat ? w1 : w_in; d = wprime;
    soff = (size_t)src_row * 128 + kc;
    doff = (size_t)n;
  } else if (i < 1835008) { int n = i - 1572864; s = w_out; d = wouth; soff = doff = (size_t)n; }
  else { int n = i - 1835008; s = w2; d = w2h; soff = doff = (size_t)n; }
  const float4* sp = reinterpret_cast<const float4*>(s) + soff * 2;
  float4 a = sp[0], b = sp[1];
  f16x8 h;
  h[0] = (_Float16)a.x; h[1] = (_Float16)a.y; h[2] = (_Float16)a.z; h[3] = (_Float16)a.w;
  h[4] = (_Float16)b.x; h[5] = (_Float16)b.y; h[6] = (_Float16)b.z; h[7] = (_Float16)b.w;
  reinterpret_cast<f16x8*>(d)[doff] = h;
}

// ---------------- gating: one wave per token, fp32 exact ----------------
__global__ __launch_bounds__(256) void gate_kernel(const float* __restrict__ x,
    const float* __restrict__ wg, const float* __restrict__ we,
    const float* __restrict__ gb, const float* __restrict__ eb,
    int* __restrict__ top2_e, float* __restrict__ top2_w) {
  const int lane = threadIdx.x & 63;
  const int token = blockIdx.x * 4 + (threadIdx.x >> 6);
  const float* xr = x + (size_t)token * C_DIM + lane * 16;
  float xv[16];
#pragma unroll
  for (int i = 0; i < 16; i += 4) {
    float4 t = *reinterpret_cast<const float4*>(xr + i);
    xv[i] = t.x; xv[i + 1] = t.y; xv[i + 2] = t.z; xv[i + 3] = t.w;
  }
  float dots[10];
#pragma unroll
  for (int g = 0; g < 10; ++g) {
    const float* wr = (g < 2 ? wg + (size_t)g * C_DIM : we + (size_t)(g - 2) * C_DIM) + lane * 16;
    float d = 0.f;
#pragma unroll
    for (int i = 0; i < 16; i += 4) {
      float4 t = *reinterpret_cast<const float4*>(wr + i);
      d += xv[i] * t.x + xv[i + 1] * t.y + xv[i + 2] * t.z + xv[i + 3] * t.w;
    }
#pragma unroll
    for (int off = 32; off > 0; off >>= 1) d += __shfl_xor(d, off);
    dots[g] = d;
  }
  if (lane != 0) return;
  float g0 = dots[0] + gb[0], g1 = dots[1] + gb[1];
  int gidx = (g0 >= g1) ? 0 : 1;   // argmax: first max wins
  float gm = fmaxf(g0, g1);
  float ex0 = expf(g0 - gm), ex1 = expf(g1 - gm);
  float gprob = (gidx == 0 ? ex0 : ex1) / (ex0 + ex1);
  const int base = gidx * 4;
  float el[4];
  float m = -1e30f;
#pragma unroll
  for (int jj = 0; jj < 4; ++jj) { el[jj] = dots[2 + base + jj] + eb[base + jj]; m = fmaxf(m, el[jj]); }
  float s = 0.f;
#pragma unroll
  for (int jj = 0; jj < 4; ++jj) { el[jj] = expf(el[jj] - m); s += el[jj]; }
  float p[8];
#pragma unroll
  for (int e = 0; e < 8; ++e) p[e] = 0.f;
#pragma unroll
  for (int jj = 0; jj < 4; ++jj) p[base + jj] = el[jj] / s * gprob;
  int i1 = 0; float v1 = -1.f;
#pragma unroll
  for (int e = 0; e < 8; ++e) if (p[e] > v1) { v1 = p[e]; i1 = e; }
  int i2 = -1; float v2 = -1.f;
#pragma unroll
  for (int e = 0; e < 8; ++e) if (e != i1 && p[e] > v2) { v2 = p[e]; i2 = e; }
  top2_e[token * 2] = i1;     top2_w[token * 2] = v1;
  top2_e[token * 2 + 1] = i2; top2_w[token * 2 + 1] = v2;
}

// ---------------- count / scan / fill (single block) ----------------
__global__ __launch_bounds__(256) void scanfill(const int* __restrict__ top2_e,
    const float* __restrict__ top2_w, int* __restrict__ offs_g,
    int* __restrict__ tok_list, float* __restrict__ scale_list,
    int* __restrict__ tok2slot) {
  __shared__ int cnt[8], offs[9], cur[8];
  const int tid = threadIdx.x;
  if (tid < 8) { cnt[tid] = 0; cur[tid] = 0; }
  __syncthreads();
  for (int i = tid; i < 2 * S_TOK; i += 256) atomicAdd(&cnt[top2_e[i]], 1);
  __syncthreads();
  if (tid == 0) {
    offs[0] = 0;
    for (int e = 0; e < 8; ++e) offs[e + 1] = offs[e] + cnt[e];
    for (int e = 0; e < 9; ++e) offs_g[e] = offs[e];
  }
  __syncthreads();
  for (int i = tid; i < 2 * S_TOK; i += 256) {
    int e = top2_e[i];
    int slot = atomicAdd(&cur[e], 1);
    int g = offs[e] + slot;
    tok_list[g] = i >> 1;
    scale_list[g] = top2_w[i];
    tok2slot[i] = g;
  }
}

// ---------------- shared GEMM plumbing (chunk-XOR LDS swizzle) ----------------
__device__ __forceinline__ f16x8 frag_ld(const _Float16* t, int row, int u) {
  return *reinterpret_cast<const f16x8*>(t + row * 64 + ((u ^ (row & 7)) << 3));
}

#define BAR __builtin_amdgcn_s_barrier()
#define LGKM0 do { asm volatile("s_waitcnt lgkmcnt(0)" ::: "memory"); \
                   __builtin_amdgcn_sched_barrier(0); } while (0)
#define PRI1 __builtin_amdgcn_s_setprio(1)
#define PRI0 __builtin_amdgcn_s_setprio(0)

// ---------------- fused swiglu GEMM: 256x256 tile, BK=64, 4-phase pipeline ----
#define STAGEA(h_, t_) do { \
  const _Float16* s_ = aS[h_] + (size_t)(t_) * 64; \
  _Float16* d_ = lds + ((t_) & 1) * 32768 + (h_) * 8192 + grp0; \
  __builtin_amdgcn_global_load_lds(AS1c(s_), AS3(d_), 16, 0, 0); \
  __builtin_amdgcn_global_load_lds(AS1c(s_ + 65536), AS3(d_ + 4096), 16, 0, 0); \
} while (0)
#define STAGEB(h_, t_) do { \
  const _Float16* s_ = bS[h_] + (size_t)(t_) * 64; \
  _Float16* d_ = lds + ((t_) & 1) * 32768 + 16384 + (h_) * 8192 + grp0; \
  __builtin_amdgcn_global_load_lds(AS1c(s_), AS3(d_), 16, 0, 0); \
  __builtin_amdgcn_global_load_lds(AS1c(s_ + 65536), AS3(d_ + 4096), 16, 0, 0); \
} while (0)

#define LDA(MB_) do { _Pragma("unroll") for (int mm = 0; mm < 4; ++mm) \
  { _Pragma("unroll") for (int ks = 0; ks < 2; ++ks) \
    af[mm][ks] = frag_ld(At, wm * 128 + (MB_) + mm * 16 + lr, ks * 4 + lq); } } while (0)
#define LDB(DST_, CB_) do { _Pragma("unroll") for (int nn = 0; nn < 2; ++nn) \
  { _Pragma("unroll") for (int ks = 0; ks < 2; ++ks) \
    DST_[nn][ks] = frag_ld(Bt, wn * 64 + (CB_) + nn * 16 + lr, ks * 4 + lq); } } while (0)
#define QUAD(MB_, BF_, NB_) do { \
  _Pragma("unroll") for (int ks = 0; ks < 2; ++ks) \
  _Pragma("unroll") for (int mm = 0; mm < 4; ++mm) \
  _Pragma("unroll") for (int nn = 0; nn < 2; ++nn) \
    acc[(MB_) + mm][(NB_) + nn] = __builtin_amdgcn_mfma_f32_16x16x32_f16( \
        af[mm][ks], BF_[nn][ks], acc[(MB_) + mm][(NB_) + nn], 0, 0, 0); \
} while (0)

__global__ __launch_bounds__(512, 2) void gemm_fused_swiglu(
    const _Float16* __restrict__ A, const _Float16* __restrict__ Wp,
    _Float16* __restrict__ H1, _Float16* __restrict__ H2) {
  __shared__ _Float16 lds[65536];  // 128 KB
  const int tid = threadIdx.x;
  const int lane = tid & 63;
  const int wid = tid >> 6;
  const int wm = wid >> 2, wn = wid & 3;   // 2 x 4 waves; per-wave 128x64 output
  const int lr = lane & 15, lq = lane >> 4;

  const int bid = blockIdx.x;
  const int xcd = bid & 7, j = bid >> 3;
  const int nb = xcd * 4 + (j & 3);  // 4 B-panels per XCD
  const int mb = j >> 2;
  const int row0 = mb * 256;
  const int colg0 = nb * 256;

  const int rA = tid >> 3, uA = tid & 7;
  const int grp0 = (tid & ~63) << 3;
  const int swz = (uA ^ (rA & 7)) << 3;
  const _Float16* aS[2];
  const _Float16* bS[2];
#pragma unroll
  for (int h = 0; h < 2; ++h) {
    aS[h] = A  + (size_t)(row0  + h * 128 + rA) * 1024 + swz;
    bS[h] = Wp + (size_t)(colg0 + h * 128 + rA) * 1024 + swz;
  }

  // prologue: stage tiles 0 and 1; wait tile 0 (8 of 16 loads)
  STAGEB(0, 0); STAGEB(1, 0); STAGEA(0, 0); STAGEA(1, 0);
  STAGEB(0, 1); STAGEB(1, 1); STAGEA(0, 1); STAGEA(1, 1);
  asm volatile("s_waitcnt vmcnt(8)" ::: "memory");
  BAR;

  f32x4 acc[8][4] = {};
  f16x8 af[4][2], bf[2][2], bf2[2][2];

  for (int t = 0; t < 16; ++t) {
    const _Float16* At = lds + (t & 1) * 32768;
    const _Float16* Bt = At + 16384;
    LDA(0); LDB(bf, 0);
    BAR; LGKM0; PRI1; QUAD(0, bf, 0); PRI0; BAR;
    LDB(bf2, 32);
    BAR; LGKM0; PRI1; QUAD(0, bf2, 2); PRI0; BAR;
    LDA(64);
    if (t < 14) { STAGEB(0, t + 2); STAGEB(1, t + 2); }
    BAR; LGKM0; PRI1; QUAD(4, bf, 0); PRI0; BAR;
    if (t < 14) { STAGEA(0, t + 2); STAGEA(1, t + 2); }
    BAR; PRI1; QUAD(4, bf2, 2); PRI0;
    if (t <= 13) { asm volatile("s_waitcnt vmcnt(8)" ::: "memory"); }
    else if (t == 14) { asm volatile("s_waitcnt vmcnt(0)" ::: "memory"); }
    BAR;
  }

  // epilogue: swiglu pairing -> XOR-swizzled LDS bounce -> coalesced 16B stores
  _Float16* Hd = (colg0 >= 4096) ? H2 : H1;
  const int col0h = (colg0 & 4095) >> 1;
#pragma unroll
  for (int mm = 0; mm < 8; ++mm)
#pragma unroll
    for (int np = 0; np < 2; ++np)
#pragma unroll
      for (int r = 0; r < 4; ++r) {
        float a = acc[mm][np * 2][r];
        float b = acc[mm][np * 2 + 1][r];
        float h = (a / (1.0f + __expf(-a))) * b;
        int row = wm * 128 + mm * 16 + lq * 4 + r;
        int hcol = wn * 32 + np * 16 + lr;
        lds[row * 128 + ((((hcol >> 3) ^ (row & 7)) << 3) | (hcol & 7))] = (_Float16)h;
      }
  __syncthreads();
#pragma unroll
  for (int i = 0; i < 8; ++i) {
    int c = tid + i * 512;                 // 4096 16B-chunks: 256 rows x 16
    int row = c >> 4, bblk = c & 15;
    f16x8 v = *reinterpret_cast<const f16x8*>(lds + row * 128 + ((bblk ^ (row & 7)) << 3));
    *reinterpret_cast<f16x8*>(Hd + (size_t)(row0 + row) * H_DIM + col0h + bblk * 8) = v;
  }
}

// ---------------- output GEMM: R2 mapping + double-buffered counted-vmcnt ----
// blocks 0..255: shared (out = H1 @ Wout^T). blocks 256..2303: expert-gathered.
#define OSTAGE(t_) do { int buf_ = ((t_) & 1) * 8192; \
  _Pragma("unroll") for (int i_ = 0; i_ < 2; ++i_) { \
    __builtin_amdgcn_global_load_lds(AS1c(aG[i_] + (size_t)(t_) * 64), AS3(aL[i_] + buf_), 16, 0, 0); \
    __builtin_amdgcn_global_load_lds(AS1c(bG[i_] + (size_t)(t_) * 64), AS3(bL[i_] + buf_), 16, 0, 0); } \
} while (0)

__global__ __launch_bounds__(512, 4) void gemm_out(
    const _Float16* __restrict__ H1, const _Float16* __restrict__ H2,
    const _Float16* __restrict__ Wout, const _Float16* __restrict__ W2,
    const int* __restrict__ offs_g, const int* __restrict__ tok_list,
    const float* __restrict__ scale_list,
    float* __restrict__ out, _Float16* __restrict__ routed) {
  __shared__ _Float16 AtF[2 * 128 * 64];
  __shared__ _Float16 BtF[2 * 128 * 64];
  __shared__ float sse[128];
  const int tid = threadIdx.x;
  const int lane = tid & 63;
  const int wid = tid >> 6;
  const int wm = wid >> 2, wn = wid & 3;
  const int lr = lane & 15, lq = lane >> 4;

  const int b = blockIdx.x;
  const bool shared_role = (b < 256);
  int rb, cb, offs_e = 0, n_e = 0;
  const _Float16* Bp;
  if (shared_role) {
    rb = b >> 3; cb = b & 7;
    Bp = Wout;
  } else {
    int eb2 = b - 256;
    int e = eb2 >> 8; rb = (eb2 >> 3) & 31; cb = eb2 & 7;
    offs_e = offs_g[e]; n_e = offs_g[e + 1] - offs_e;
    if (rb * 128 >= n_e) return;   // data-dependent early exit (pre-barrier)
    Bp = W2 + (size_t)e * C_DIM * H_DIM;
    if (tid < 128) {
      int lrr = rb * 128 + tid;
      sse[tid] = (lrr < n_e) ? scale_list[offs_e + lrr] : 0.f;
    }
  }

  const _Float16* aG[2];
  const _Float16* bG[2];
  _Float16* aL[2];
  _Float16* bL[2];
#pragma unroll
  for (int i = 0; i < 2; ++i) {
    int c = tid + i * 512;
    int row = c >> 3, u = c & 7;
    int swz = (u ^ (row & 7)) << 3;
    const _Float16* rowbase;
    if (shared_role) {
      rowbase = H1 + (size_t)(rb * 128 + row) * H_DIM;
    } else {
      int lrr = rb * 128 + row;
      int gs = offs_e + (lrr < n_e ? lrr : n_e - 1);
      rowbase = H2 + (size_t)tok_list[gs] * H_DIM;
    }
    aG[i] = rowbase + swz;
    bG[i] = Bp + (size_t)(cb * 128 + row) * H_DIM + swz;
    aL[i] = AtF + ((c & ~63) << 3);
    bL[i] = BtF + ((c & ~63) << 3);
  }

  // prologue: stage tiles 0,1 (4 loads each); wait tile 0
  OSTAGE(0); OSTAGE(1);
  asm volatile("s_waitcnt vmcnt(4)" ::: "memory");
  BAR;

  f32x4 acc[4][2] = {};
  for (int t = 0; t < 32; ++t) {
    const _Float16* Ab = AtF + (t & 1) * 8192;
    const _Float16* Bb = BtF + (t & 1) * 8192;
    f16x8 af[4][2], bfr[2][2];
    // ph0: read ALL fragments (both K-slices) for this tile
#pragma unroll
    for (int m = 0; m < 4; ++m)
#pragma unroll
      for (int ks = 0; ks < 2; ++ks)
        af[m][ks] = frag_ld(Ab, wm * 64 + m * 16 + lr, ks * 4 + lq);
#pragma unroll
    for (int n = 0; n < 2; ++n)
#pragma unroll
      for (int ks = 0; ks < 2; ++ks)
        bfr[n][ks] = frag_ld(Bb, wn * 32 + n * 16 + lr, ks * 4 + lq);
    BAR; LGKM0;
    PRI1;
#pragma unroll
    for (int m = 0; m < 4; ++m)
#pragma unroll
      for (int n = 0; n < 2; ++n)
        acc[m][n] = __builtin_amdgcn_mfma_f32_16x16x32_f16(af[m][0], bfr[n][0], acc[m][n], 0, 0, 0);
    PRI0;
    BAR;  // beyond this point every wave's LDS reads of this buffer are complete
    // ph1: stage t+2 into same-parity buffer (race-free: all reads retired)
    if (t < 30) OSTAGE(t + 2);
    BAR;
    PRI1;
#pragma unroll
    for (int m = 0; m < 4; ++m)
#pragma unroll
      for (int n = 0; n < 2; ++n)
        acc[m][n] = __builtin_amdgcn_mfma_f32_16x16x32_f16(af[m][1], bfr[n][1], acc[m][n], 0, 0, 0);
    PRI0;
    if (t < 30) { asm volatile("s_waitcnt vmcnt(4)" ::: "memory"); }
    else if (t == 30) { asm volatile("s_waitcnt vmcnt(0)" ::: "memory"); }
    BAR;
  }

#pragma unroll
  for (int m = 0; m < 4; ++m)
#pragma unroll
    for (int n = 0; n < 2; ++n)
#pragma unroll
      for (int r = 0; r < 4; ++r) {
        int rloc = wm * 64 + m * 16 + (lq << 2) + r;
        int col = cb * 128 + wn * 32 + n * 16 + lr;
        if (shared_role) {
          out[(size_t)(rb * 128 + rloc) * C_DIM + col] = acc[m][n][r];
        } else {
          int lrr = rb * 128 + rloc;
          if (lrr < n_e)
            routed[(size_t)(offs_e + lrr) * C_DIM + col] =
                (_Float16)(sse[rloc] * acc[m][n][r]);
        }
      }
}

// ---------------- final gather-add: out[t] += routed[slot0] + routed[slot1] ----
__global__ __launch_bounds__(256) void combine_final(float* __restrict__ out,
    const _Float16* __restrict__ routed, const int* __restrict__ tok2slot) {
  const int t = blockIdx.x * 2 + (threadIdx.x >> 7);
  const int cp = (threadIdx.x & 127) << 3;
  const int s0 = tok2slot[t * 2], s1 = tok2slot[t * 2 + 1];
  f16x8 r0 = *reinterpret_cast<const f16x8*>(routed + (size_t)s0 * C_DIM + cp);
  f16x8 r1 = *reinterpret_cast<const f16x8*>(routed + (size_t)s1 * C_DIM + cp);
  float* op = out + (size_t)t * C_DIM + cp;
  float4 o0 = *reinterpret_cast<const float4*>(op);
  float4 o1 = *reinterpret_cast<const float4*>(op + 4);
  o0.x += (float)r0[0] + (float)r1[0];
  o0.y += (float)r0[1] + (float)r1[1];
  o0.z += (float)r0[2] + (float)r1[2];
  o0.w += (float)r0[3] + (float)r1[3];
  o1.x += (float)r0[4] + (float)r1[4];
  o1.y += (float)r0[5] + (float)r1[5];
  o1.z += (float)r0[6] + (float)r1[6];
  o1.w += (float)r0[7] + (float)r1[7];
  *reinterpret_cast<float4*>(op) = o0;
  *reinterpret_cast<float4*>(op + 4) = o1;
}

extern "C" void kernel_launch(void* const* d_in, const int* in_sizes, int n_in,
                              void* d_out, int out_size, void* d_ws, size_t ws_size,
                              hipStream_t stream) {
  const float* x     = (const float*)d_in[0];
  const float* w_in  = (const float*)d_in[1];
  const float* w_out = (const float*)d_in[2];
  const float* w1    = (const float*)d_in[3];
  const float* w2    = (const float*)d_in[4];
  const float* wg    = (const float*)d_in[5];
  const float* we    = (const float*)d_in[6];
  const float* gb    = (const float*)d_in[7];
  const float* eb    = (const float*)d_in[8];
  float* out = (float*)d_out;

  char* ws = (char*)d_ws;
  const size_t MB = 1u << 20;
  _Float16* xh     = (_Float16*)(ws + 0 * MB);    // 8 MB  [4096,1024]
  _Float16* wprime = (_Float16*)(ws + 8 * MB);    // 16 MB [8192,1024] permuted
  _Float16* routed = (_Float16*)(ws + 0 * MB);    // 16 MB [8192,1024] (overlay)
  _Float16* wouth  = (_Float16*)(ws + 24 * MB);   // 4 MB  [1024,2048]
  _Float16* w2h    = (_Float16*)(ws + 28 * MB);   // 32 MB [8,1024,2048]
  _Float16* H1     = (_Float16*)(ws + 60 * MB);   // 16 MB [4096,2048]
  _Float16* H2     = (_Float16*)(ws + 76 * MB);   // 16 MB [4096,2048]
  char* sm = ws + 92 * MB;
  int*   offs_g     = (int*)(sm);
  int*   top2_e     = (int*)(sm + 64);
  float* top2_w     = (float*)(sm + 64 + 32768);
  int*   tok_list   = (int*)(sm + 64 + 65536);
  float* scale_list = (float*)(sm + 64 + 98304);
  int*   tok2slot   = (int*)(sm + 64 + 131072);

  cvt_all<<<15360, 256, 0, stream>>>(x, w_in, w1, w_out, w2,
                                     xh, wprime, wouth, w2h);
  gate_kernel<<<1024, 256, 0, stream>>>(x, wg, we, gb, eb, top2_e, top2_w);
  scanfill<<<1, 256, 0, stream>>>(top2_e, top2_w, offs_g, tok_list,
                                  scale_list, tok2slot);

  gemm_fused_swiglu<<<512, 512, 0, stream>>>(xh, wprime, H1, H2);

  gemm_out<<<2304, 512, 0, stream>>>(H1, H2, wouth, w2h, offs_g, tok_list,
                                     scale_list, out, routed);
  combine_final<<<2048, 256, 0, stream>>>(out, routed, tok2slot);
}

// Round 5
// 339.242 us; speedup vs baseline: 1.0254x; 1.0254x over previous
//
#include <hip/hip_runtime.h>
#include <math.h>

// HierDSFeedForward — round 5: gemm_out rebuilt on the 256²/4-phase counted-vmcnt
// pipeline (same proven loop as swiglu), padded expert segments, one grid round.
// S=4096 tokens, C=1024, H=2048, 8 experts (2 groups x 4), top-2.

#define C_DIM 1024
#define H_DIM 2048
#define S_TOK 4096

typedef _Float16 f16x8 __attribute__((ext_vector_type(8)));
typedef float f32x4 __attribute__((ext_vector_type(4)));

#define AS3(p) ((__attribute__((address_space(3))) void*)(p))
#define AS1c(p) ((const __attribute__((address_space(1))) void*)(p))

// ---------------- fused fp32 -> fp16 convert (+ swiglu-pair row permutation) ----
__global__ __launch_bounds__(256) void cvt_all(
    const float* __restrict__ x, const float* __restrict__ w_in,
    const float* __restrict__ w1, const float* __restrict__ w_out,
    const float* __restrict__ w2, _Float16* __restrict__ xh,
    _Float16* __restrict__ wprime, _Float16* __restrict__ wouth,
    _Float16* __restrict__ w2h) {
  int i = blockIdx.x * 256 + threadIdx.x;  // 8-element chunk index
  const float* s; _Float16* d; size_t soff, doff;
  if (i < 524288) { s = x; d = xh; soff = doff = (size_t)i; }
  else if (i < 1572864) {
    int n = i - 524288;
    int out_row = n >> 7, kc = n & 127;
    int wmat = out_row >> 12, r = out_row & 4095;
    int g = r >> 5, ii = r & 31;
    int src_row = (ii < 16) ? (g * 16 + ii) : (2048 + g * 16 + (ii - 16));
    s = wmat ? w1 : w_in; d = wprime;
    soff = (size_t)src_row * 128 + kc;
    doff = (size_t)n;
  } else if (i < 1835008) { int n = i - 1572864; s = w_out; d = wouth; soff = doff = (size_t)n; }
  else { int n = i - 1835008; s = w2; d = w2h; soff = doff = (size_t)n; }
  const float4* sp = reinterpret_cast<const float4*>(s) + soff * 2;
  float4 a = sp[0], b = sp[1];
  f16x8 h;
  h[0] = (_Float16)a.x; h[1] = (_Float16)a.y; h[2] = (_Float16)a.z; h[3] = (_Float16)a.w;
  h[4] = (_Float16)b.x; h[5] = (_Float16)b.y; h[6] = (_Float16)b.z; h[7] = (_Float16)b.w;
  reinterpret_cast<f16x8*>(d)[doff] = h;
}

// ---------------- gating: one wave per token, fp32 exact ----------------
__global__ __launch_bounds__(256) void gate_kernel(const float* __restrict__ x,
    const float* __restrict__ wg, const float* __restrict__ we,
    const float* __restrict__ gb, const float* __restrict__ eb,
    int* __restrict__ top2_e, float* __restrict__ top2_w) {
  const int lane = threadIdx.x & 63;
  const int token = blockIdx.x * 4 + (threadIdx.x >> 6);
  const float* xr = x + (size_t)token * C_DIM + lane * 16;
  float xv[16];
#pragma unroll
  for (int i = 0; i < 16; i += 4) {
    float4 t = *reinterpret_cast<const float4*>(xr + i);
    xv[i] = t.x; xv[i + 1] = t.y; xv[i + 2] = t.z; xv[i + 3] = t.w;
  }
  float dots[10];
#pragma unroll
  for (int g = 0; g < 10; ++g) {
    const float* wr = (g < 2 ? wg + (size_t)g * C_DIM : we + (size_t)(g - 2) * C_DIM) + lane * 16;
    float d = 0.f;
#pragma unroll
    for (int i = 0; i < 16; i += 4) {
      float4 t = *reinterpret_cast<const float4*>(wr + i);
      d += xv[i] * t.x + xv[i + 1] * t.y + xv[i + 2] * t.z + xv[i + 3] * t.w;
    }
#pragma unroll
    for (int off = 32; off > 0; off >>= 1) d += __shfl_xor(d, off);
    dots[g] = d;
  }
  if (lane != 0) return;
  float g0 = dots[0] + gb[0], g1 = dots[1] + gb[1];
  int gidx = (g0 >= g1) ? 0 : 1;   // argmax: first max wins
  float gm = fmaxf(g0, g1);
  float ex0 = expf(g0 - gm), ex1 = expf(g1 - gm);
  float gprob = (gidx == 0 ? ex0 : ex1) / (ex0 + ex1);
  const int base = gidx * 4;
  float el[4];
  float m = -1e30f;
#pragma unroll
  for (int jj = 0; jj < 4; ++jj) { el[jj] = dots[2 + base + jj] + eb[base + jj]; m = fmaxf(m, el[jj]); }
  float s = 0.f;
#pragma unroll
  for (int jj = 0; jj < 4; ++jj) { el[jj] = expf(el[jj] - m); s += el[jj]; }
  float p[8];
#pragma unroll
  for (int e = 0; e < 8; ++e) p[e] = 0.f;
#pragma unroll
  for (int jj = 0; jj < 4; ++jj) p[base + jj] = el[jj] / s * gprob;
  int i1 = 0; float v1 = -1.f;
#pragma unroll
  for (int e = 0; e < 8; ++e) if (p[e] > v1) { v1 = p[e]; i1 = e; }
  int i2 = -1; float v2 = -1.f;
#pragma unroll
  for (int e = 0; e < 8; ++e) if (e != i1 && p[e] > v2) { v2 = p[e]; i2 = e; }
  top2_e[token * 2] = i1;     top2_w[token * 2] = v1;
  top2_e[token * 2 + 1] = i2; top2_w[token * 2 + 1] = v2;
}

// ---------------- count / scan(pad-256) / fill (single block) ----------------
__global__ __launch_bounds__(256) void scanfill(const int* __restrict__ top2_e,
    const float* __restrict__ top2_w, int* __restrict__ offs_pad,
    int* __restrict__ tok_list, float* __restrict__ scale_list,
    int* __restrict__ tok2slot) {
  __shared__ int cnt[8], offs[9], cur[8];
  const int tid = threadIdx.x;
  if (tid < 8) { cnt[tid] = 0; cur[tid] = 0; }
  __syncthreads();
  for (int i = tid; i < 2 * S_TOK; i += 256) atomicAdd(&cnt[top2_e[i]], 1);
  __syncthreads();
  if (tid == 0) {
    offs[0] = 0;
    for (int e = 0; e < 8; ++e) offs[e + 1] = offs[e] + ((cnt[e] + 255) & ~255);
    for (int e = 0; e < 9; ++e) offs_pad[e] = offs[e];
  }
  __syncthreads();
  const int ptot = offs[8];
  for (int i = tid; i < ptot; i += 256) { tok_list[i] = 0; scale_list[i] = 0.f; }
  __syncthreads();
  for (int i = tid; i < 2 * S_TOK; i += 256) {
    int e = top2_e[i];
    int slot = atomicAdd(&cur[e], 1);
    int g = offs[e] + slot;
    tok_list[g] = i >> 1;
    scale_list[g] = top2_w[i];
    tok2slot[i] = g;
  }
}

// ---------------- shared GEMM plumbing (chunk-XOR LDS swizzle) ----------------
__device__ __forceinline__ f16x8 frag_ld(const _Float16* t, int row, int u) {
  return *reinterpret_cast<const f16x8*>(t + row * 64 + ((u ^ (row & 7)) << 3));
}

#define BAR __builtin_amdgcn_s_barrier()
#define LGKM0 do { asm volatile("s_waitcnt lgkmcnt(0)" ::: "memory"); \
                   __builtin_amdgcn_sched_barrier(0); } while (0)
#define PRI1 __builtin_amdgcn_s_setprio(1)
#define PRI0 __builtin_amdgcn_s_setprio(0)

#define LDA(MB_) do { _Pragma("unroll") for (int mm = 0; mm < 4; ++mm) \
  { _Pragma("unroll") for (int ks = 0; ks < 2; ++ks) \
    af[mm][ks] = frag_ld(At, wm * 128 + (MB_) + mm * 16 + lr, ks * 4 + lq); } } while (0)
#define LDB(DST_, CB_) do { _Pragma("unroll") for (int nn = 0; nn < 2; ++nn) \
  { _Pragma("unroll") for (int ks = 0; ks < 2; ++ks) \
    DST_[nn][ks] = frag_ld(Bt, wn * 64 + (CB_) + nn * 16 + lr, ks * 4 + lq); } } while (0)
#define QUAD(MB_, BF_, NB_) do { \
  _Pragma("unroll") for (int ks = 0; ks < 2; ++ks) \
  _Pragma("unroll") for (int mm = 0; mm < 4; ++mm) \
  _Pragma("unroll") for (int nn = 0; nn < 2; ++nn) \
    acc[(MB_) + mm][(NB_) + nn] = __builtin_amdgcn_mfma_f32_16x16x32_f16( \
        af[mm][ks], BF_[nn][ks], acc[(MB_) + mm][(NB_) + nn], 0, 0, 0); \
} while (0)

// ---------------- fused swiglu GEMM: 256x256 tile, BK=64, 4-phase pipeline ----
#define STAGEA(h_, t_) do { \
  const _Float16* s_ = aS[h_] + (size_t)(t_) * 64; \
  _Float16* d_ = lds + ((t_) & 1) * 32768 + (h_) * 8192 + grp0; \
  __builtin_amdgcn_global_load_lds(AS1c(s_), AS3(d_), 16, 0, 0); \
  __builtin_amdgcn_global_load_lds(AS1c(s_ + 65536), AS3(d_ + 4096), 16, 0, 0); \
} while (0)
#define STAGEB(h_, t_) do { \
  const _Float16* s_ = bS[h_] + (size_t)(t_) * 64; \
  _Float16* d_ = lds + ((t_) & 1) * 32768 + 16384 + (h_) * 8192 + grp0; \
  __builtin_amdgcn_global_load_lds(AS1c(s_), AS3(d_), 16, 0, 0); \
  __builtin_amdgcn_global_load_lds(AS1c(s_ + 65536), AS3(d_ + 4096), 16, 0, 0); \
} while (0)

__global__ __launch_bounds__(512, 2) void gemm_fused_swiglu(
    const _Float16* __restrict__ A, const _Float16* __restrict__ Wp,
    _Float16* __restrict__ H1, _Float16* __restrict__ H2) {
  __shared__ _Float16 lds[65536];  // 128 KB
  const int tid = threadIdx.x;
  const int lane = tid & 63;
  const int wid = tid >> 6;
  const int wm = wid >> 2, wn = wid & 3;   // 2 x 4 waves; per-wave 128x64 output
  const int lr = lane & 15, lq = lane >> 4;

  const int bid = blockIdx.x;
  const int xcd = bid & 7, j = bid >> 3;
  const int nb = xcd * 4 + (j & 3);  // 4 B-panels per XCD
  const int mb = j >> 2;
  const int row0 = mb * 256;
  const int colg0 = nb * 256;

  const int rA = tid >> 3, uA = tid & 7;
  const int grp0 = (tid & ~63) << 3;
  const int swz = (uA ^ (rA & 7)) << 3;
  const _Float16* aS[2];
  const _Float16* bS[2];
#pragma unroll
  for (int h = 0; h < 2; ++h) {
    aS[h] = A  + (size_t)(row0  + h * 128 + rA) * 1024 + swz;
    bS[h] = Wp + (size_t)(colg0 + h * 128 + rA) * 1024 + swz;
  }

  STAGEB(0, 0); STAGEB(1, 0); STAGEA(0, 0); STAGEA(1, 0);
  STAGEB(0, 1); STAGEB(1, 1); STAGEA(0, 1); STAGEA(1, 1);
  asm volatile("s_waitcnt vmcnt(8)" ::: "memory");
  BAR;

  f32x4 acc[8][4] = {};
  f16x8 af[4][2], bf[2][2], bf2[2][2];

  for (int t = 0; t < 16; ++t) {
    const _Float16* At = lds + (t & 1) * 32768;
    const _Float16* Bt = At + 16384;
    LDA(0); LDB(bf, 0);
    BAR; LGKM0; PRI1; QUAD(0, bf, 0); PRI0; BAR;
    LDB(bf2, 32);
    BAR; LGKM0; PRI1; QUAD(0, bf2, 2); PRI0; BAR;
    LDA(64);
    if (t < 14) { STAGEB(0, t + 2); STAGEB(1, t + 2); }
    BAR; LGKM0; PRI1; QUAD(4, bf, 0); PRI0; BAR;
    if (t < 14) { STAGEA(0, t + 2); STAGEA(1, t + 2); }
    BAR; PRI1; QUAD(4, bf2, 2); PRI0;
    if (t <= 13) { asm volatile("s_waitcnt vmcnt(8)" ::: "memory"); }
    else if (t == 14) { asm volatile("s_waitcnt vmcnt(0)" ::: "memory"); }
    BAR;
  }

  // epilogue: swiglu pairing -> XOR-swizzled LDS bounce -> coalesced 16B stores
  _Float16* Hd = (colg0 >= 4096) ? H2 : H1;
  const int col0h = (colg0 & 4095) >> 1;
#pragma unroll
  for (int mm = 0; mm < 8; ++mm)
#pragma unroll
    for (int np = 0; np < 2; ++np)
#pragma unroll
      for (int r = 0; r < 4; ++r) {
        float a = acc[mm][np * 2][r];
        float b = acc[mm][np * 2 + 1][r];
        float h = (a / (1.0f + __expf(-a))) * b;
        int row = wm * 128 + mm * 16 + lq * 4 + r;
        int hcol = wn * 32 + np * 16 + lr;
        lds[row * 128 + ((((hcol >> 3) ^ (row & 7)) << 3) | (hcol & 7))] = (_Float16)h;
      }
  __syncthreads();
#pragma unroll
  for (int i = 0; i < 8; ++i) {
    int c = tid + i * 512;                 // 4096 16B-chunks: 256 rows x 16
    int row = c >> 4, bblk = c & 15;
    f16x8 v = *reinterpret_cast<const f16x8*>(lds + row * 128 + ((bblk ^ (row & 7)) << 3));
    *reinterpret_cast<f16x8*>(Hd + (size_t)(row0 + row) * H_DIM + col0h + bblk * 8) = v;
  }
}

// ---------------- output GEMM, 256² 4-phase: shared + padded expert segments --
// blocks 0..63: out[sb*256.., cb*256..] = H1 @ Wout^T (sb=b>>2, cb=b&3)
// blocks 64..223: super-block sb of padded expert slots (never straddles experts)
#define OSTGB(i_, t_) __builtin_amdgcn_global_load_lds( \
    AS1c(bP[i_] + (size_t)(t_) * 64), \
    AS3(lds + ((t_) & 1) * 32768 + 16384 + (i_) * 4096 + grp0), 16, 0, 0)
#define OSTGA(i_, t_) __builtin_amdgcn_global_load_lds( \
    AS1c(aP[i_] + (size_t)(t_) * 64), \
    AS3(lds + ((t_) & 1) * 32768 + (i_) * 4096 + grp0), 16, 0, 0)

__global__ __launch_bounds__(512, 2) void gemm_out256(
    const _Float16* __restrict__ H1, const _Float16* __restrict__ H2,
    const _Float16* __restrict__ Wout, const _Float16* __restrict__ W2,
    const int* __restrict__ offs_pad, const int* __restrict__ tok_list,
    const float* __restrict__ scale_list,
    float* __restrict__ out, _Float16* __restrict__ routed) {
  __shared__ _Float16 lds[65536];  // 128 KB
  __shared__ float sse[256];
  const int tid = threadIdx.x;
  const int lane = tid & 63;
  const int wid = tid >> 6;
  const int wm = wid >> 2, wn = wid & 3;
  const int lr = lane & 15, lq = lane >> 4;

  const int b = blockIdx.x;
  const bool shared_role = (b < 64);
  int sb, cb, p0 = 0;
  const _Float16* Bp;
  if (shared_role) {
    sb = b >> 2; cb = b & 3;
    Bp = Wout;
  } else {
    int idx = b - 64;
    sb = idx >> 2; cb = idx & 3;
    p0 = sb * 256;
    if (p0 >= offs_pad[8]) return;   // uniform early exit, before any barrier
    int e = 0;
#pragma unroll
    for (int k = 1; k < 8; ++k) e += (offs_pad[k] <= p0) ? 1 : 0;
    Bp = W2 + (size_t)e * C_DIM * H_DIM;
    if (tid < 256) sse[tid] = scale_list[p0 + tid];
  }

  const int rA = tid >> 3, uA = tid & 7;
  const int grp0 = (tid & ~63) << 3;
  const int swz = (uA ^ (rA & 7)) << 3;
  const _Float16* aP[4];
  const _Float16* bP[4];
#pragma unroll
  for (int h = 0; h < 2; ++h)
#pragma unroll
    for (int s = 0; s < 2; ++s) {
      int arow = h * 128 + s * 64 + rA;
      const _Float16* abase;
      if (shared_role) abase = H1 + (size_t)(sb * 256 + arow) * H_DIM;
      else             abase = H2 + (size_t)tok_list[p0 + arow] * H_DIM;
      aP[h * 2 + s] = abase + swz;
      bP[h * 2 + s] = Bp + (size_t)(cb * 256 + arow) * H_DIM + swz;
    }

  // prologue: stage tiles 0,1 (8 loads each); wait tile 0
  OSTGB(0, 0); OSTGB(1, 0); OSTGB(2, 0); OSTGB(3, 0);
  OSTGA(0, 0); OSTGA(1, 0); OSTGA(2, 0); OSTGA(3, 0);
  OSTGB(0, 1); OSTGB(1, 1); OSTGB(2, 1); OSTGB(3, 1);
  OSTGA(0, 1); OSTGA(1, 1); OSTGA(2, 1); OSTGA(3, 1);
  asm volatile("s_waitcnt vmcnt(8)" ::: "memory");
  BAR;

  f32x4 acc[8][4] = {};
  f16x8 af[4][2], bf[2][2], bf2[2][2];

  for (int t = 0; t < 32; ++t) {
    const _Float16* At = lds + (t & 1) * 32768;
    const _Float16* Bt = At + 16384;
    LDA(0); LDB(bf, 0);
    BAR; LGKM0; PRI1; QUAD(0, bf, 0); PRI0; BAR;
    LDB(bf2, 32);
    BAR; LGKM0; PRI1; QUAD(0, bf2, 2); PRI0; BAR;
    LDA(64);
    if (t < 30) { OSTGB(0, t + 2); OSTGB(1, t + 2); OSTGB(2, t + 2); OSTGB(3, t + 2); }
    BAR; LGKM0; PRI1; QUAD(4, bf, 0); PRI0; BAR;
    if (t < 30) { OSTGA(0, t + 2); OSTGA(1, t + 2); OSTGA(2, t + 2); OSTGA(3, t + 2); }
    BAR; PRI1; QUAD(4, bf2, 2); PRI0;
    if (t <= 29) { asm volatile("s_waitcnt vmcnt(8)" ::: "memory"); }
    else if (t == 30) { asm volatile("s_waitcnt vmcnt(0)" ::: "memory"); }
    BAR;
  }

  if (shared_role) {
#pragma unroll
    for (int mm = 0; mm < 8; ++mm)
#pragma unroll
      for (int nn = 0; nn < 4; ++nn)
#pragma unroll
        for (int r = 0; r < 4; ++r) {
          int rloc = wm * 128 + mm * 16 + lq * 4 + r;
          int col = cb * 256 + wn * 64 + nn * 16 + lr;
          out[(size_t)(sb * 256 + rloc) * C_DIM + col] = acc[mm][nn][r];
        }
  } else {
    // scale + pack to LDS (XOR-swizzled), then coalesced 16B stores
#pragma unroll
    for (int mm = 0; mm < 8; ++mm)
#pragma unroll
      for (int nn = 0; nn < 4; ++nn)
#pragma unroll
        for (int r = 0; r < 4; ++r) {
          int rloc = wm * 128 + mm * 16 + lq * 4 + r;
          int col = wn * 64 + nn * 16 + lr;
          float v = sse[rloc] * acc[mm][nn][r];
          int u = col >> 3;
          int us = (u & 24) | ((u ^ rloc) & 7);
          lds[rloc * 256 + (us << 3) + (col & 7)] = (_Float16)v;
        }
    __syncthreads();
#pragma unroll
    for (int i = 0; i < 16; ++i) {
      int c = tid + i * 512;               // 8192 chunks: 256 rows x 32 units
      int row = c >> 5, u = c & 31;
      int us = (u & 24) | ((u ^ row) & 7);
      f16x8 v = *reinterpret_cast<const f16x8*>(lds + row * 256 + (us << 3));
      *reinterpret_cast<f16x8*>(routed + (size_t)(p0 + row) * C_DIM + cb * 256 + u * 8) = v;
    }
  }
}

// ---------------- final gather-add: out[t] += routed[slot0] + routed[slot1] ----
__global__ __launch_bounds__(256) void combine_final(float* __restrict__ out,
    const _Float16* __restrict__ routed, const int* __restrict__ tok2slot) {
  const int t = blockIdx.x * 2 + (threadIdx.x >> 7);
  const int cp = (threadIdx.x & 127) << 3;
  const int s0 = tok2slot[t * 2], s1 = tok2slot[t * 2 + 1];
  f16x8 r0 = *reinterpret_cast<const f16x8*>(routed + (size_t)s0 * C_DIM + cp);
  f16x8 r1 = *reinterpret_cast<const f16x8*>(routed + (size_t)s1 * C_DIM + cp);
  float* op = out + (size_t)t * C_DIM + cp;
  float4 o0 = *reinterpret_cast<const float4*>(op);
  float4 o1 = *reinterpret_cast<const float4*>(op + 4);
  o0.x += (float)r0[0] + (float)r1[0];
  o0.y += (float)r0[1] + (float)r1[1];
  o0.z += (float)r0[2] + (float)r1[2];
  o0.w += (float)r0[3] + (float)r1[3];
  o1.x += (float)r0[4] + (float)r1[4];
  o1.y += (float)r0[5] + (float)r1[5];
  o1.z += (float)r0[6] + (float)r1[6];
  o1.w += (float)r0[7] + (float)r1[7];
  *reinterpret_cast<float4*>(op) = o0;
  *reinterpret_cast<float4*>(op + 4) = o1;
}

extern "C" void kernel_launch(void* const* d_in, const int* in_sizes, int n_in,
                              void* d_out, int out_size, void* d_ws, size_t ws_size,
                              hipStream_t stream) {
  const float* x     = (const float*)d_in[0];
  const float* w_in  = (const float*)d_in[1];
  const float* w_out = (const float*)d_in[2];
  const float* w1    = (const float*)d_in[3];
  const float* w2    = (const float*)d_in[4];
  const float* wg    = (const float*)d_in[5];
  const float* we    = (const float*)d_in[6];
  const float* gb    = (const float*)d_in[7];
  const float* eb    = (const float*)d_in[8];
  float* out = (float*)d_out;

  char* ws = (char*)d_ws;
  const size_t MB = 1u << 20;
  _Float16* xh     = (_Float16*)(ws + 0 * MB);    // 8 MB  [4096,1024]
  _Float16* wprime = (_Float16*)(ws + 8 * MB);    // 16 MB [8192,1024] permuted
  _Float16* routed = (_Float16*)(ws + 0 * MB);    // 20 MB [10240,1024] (overlay, dead-after-swiglu region)
  _Float16* wouth  = (_Float16*)(ws + 24 * MB);   // 4 MB  [1024,2048]
  _Float16* w2h    = (_Float16*)(ws + 28 * MB);   // 32 MB [8,1024,2048]
  _Float16* H1     = (_Float16*)(ws + 60 * MB);   // 16 MB [4096,2048]
  _Float16* H2     = (_Float16*)(ws + 76 * MB);   // 16 MB [4096,2048]
  char* sm = ws + 92 * MB;
  int*   offs_pad   = (int*)(sm);                  // 64 B (9 used)
  int*   top2_e     = (int*)(sm + 1024);           // 32 KB
  float* top2_w     = (float*)(sm + 1024 + 32768); // 32 KB
  int*   tok_list   = (int*)(sm + 1024 + 65536);   // 40 KB (10240 padded slots)
  float* scale_list = (float*)(sm + 1024 + 106496);// 40 KB
  int*   tok2slot   = (int*)(sm + 1024 + 147456);  // 32 KB

  cvt_all<<<15360, 256, 0, stream>>>(x, w_in, w1, w_out, w2,
                                     xh, wprime, wouth, w2h);
  gate_kernel<<<1024, 256, 0, stream>>>(x, wg, we, gb, eb, top2_e, top2_w);
  scanfill<<<1, 256, 0, stream>>>(top2_e, top2_w, offs_pad, tok_list,
                                  scale_list, tok2slot);

  gemm_fused_swiglu<<<512, 512, 0, stream>>>(xh, wprime, H1, H2);

  gemm_out256<<<224, 512, 0, stream>>>(H1, H2, wouth, w2h, offs_pad, tok_list,
                                       scale_list, out, routed);
  combine_final<<<2048, 256, 0, stream>>>(out, routed, tok2slot);
}